// Round 2
// baseline (523.645 us; speedup 1.0000x reference)
//
#include <hip/hip_runtime.h>

typedef unsigned short ushort_t;
typedef __bf16 bf16x8 __attribute__((ext_vector_type(8)));
typedef float f4v __attribute__((ext_vector_type(4)));

#define B_ 2
#define T_ 4096
#define C_ 768
#define H_ 12
#define D_ 64
#define BT_ (B_*T_)

// workspace layout (bytes)
#define XB_SZ   (BT_*C_*2)            // 12,582,912
#define WT_SZ   (C_*C_*2)             // 1,179,648
#define QKV_SZ  (BT_*C_*2)            // 12,582,912
#define WS_XB   0
#define WS_WT   (WS_XB + XB_SZ)
#define WS_Q    (WS_WT + 4*WT_SZ)
#define WS_K    (WS_Q + QKV_SZ)
#define WS_V    (WS_K + QKV_SZ)
#define WS_AO   (WS_V + QKV_SZ)
#define WS_TOTAL (WS_AO + QKV_SZ)

__device__ __forceinline__ ushort_t f2bf(float f) {
    unsigned u = __float_as_uint(f);
    u += 0x7FFFu + ((u >> 16) & 1u);
    return (ushort_t)(u >> 16);
}

__global__ __launch_bounds__(256) void k_convert_x(const float* __restrict__ x,
                                                   ushort_t* __restrict__ xb, int n4) {
    int i = blockIdx.x * 256 + threadIdx.x;
    if (i >= n4) return;
    float4 v = ((const float4*)x)[i];
    ushort4 o;
    o.x = f2bf(v.x); o.y = f2bf(v.y); o.z = f2bf(v.z); o.w = f2bf(v.w);
    ((ushort4*)xb)[i] = o;
}

// Wt[n][k] = bf16(W[k][n]), four weights
__global__ __launch_bounds__(256) void k_wt(const float* __restrict__ w0,
                                            const float* __restrict__ w1,
                                            const float* __restrict__ w2,
                                            const float* __restrict__ w3,
                                            ushort_t* __restrict__ wt) {
    __shared__ float tile[32][33];
    int wi = blockIdx.z;
    const float* W = (wi == 0) ? w0 : (wi == 1) ? w1 : (wi == 2) ? w2 : w3;
    ushort_t* out = wt + wi * C_ * C_;
    int k0 = blockIdx.x * 32, n0 = blockIdx.y * 32;
    int tx = threadIdx.x & 31, ty = threadIdx.x >> 5;  // ty 0..7
#pragma unroll
    for (int i = 0; i < 4; ++i) {
        int kr = ty * 4 + i;
        tile[kr][tx] = W[(k0 + kr) * C_ + n0 + tx];
    }
    __syncthreads();
#pragma unroll
    for (int i = 0; i < 4; ++i) {
        int nr = ty * 4 + i;
        out[(n0 + nr) * C_ + k0 + tx] = f2bf(tile[tx][nr]);
    }
}

// 128x128 tile GEMM, 4 waves (2x2), wave computes 64x64; BK=64; swizzled LDS.
// z=0:Q (scaled 0.125), z=1:K, z=2:V stored transposed [B,H,D,T]
__global__ __launch_bounds__(256) void k_gemm_qkv(
    const ushort_t* __restrict__ Xb, const ushort_t* __restrict__ WtAll,
    const float* __restrict__ bq, const float* __restrict__ bk, const float* __restrict__ bv,
    ushort_t* __restrict__ Qo, ushort_t* __restrict__ Ko, ushort_t* __restrict__ Vo) {
    __shared__ ushort_t lsA[128 * 64];
    __shared__ ushort_t lsB[128 * 64];
    char* lsAb = (char*)lsA;
    char* lsBb = (char*)lsB;
    const int z = blockIdx.z;
    const ushort_t* Wt = WtAll + z * C_ * C_;
    const float* bias = (z == 0) ? bq : (z == 1) ? bk : bv;
    const int m0 = blockIdx.x * 128, n0 = blockIdx.y * 128;
    const int tid = threadIdx.x;
    const int w = tid >> 6, lane = tid & 63, lg = lane >> 4, lr = lane & 15;
    const int wm = w >> 1, wn = w & 1;
    f4v acc[4][4] = {};
    for (int ks = 0; ks < 12; ++ks) {
        const int k0 = ks * 64;
        __syncthreads();
#pragma unroll
        for (int i = 0; i < 4; ++i) {
            int s = tid + 256 * i;
            int r = s >> 3, c16 = s & 7;
            uint4 va = *(const uint4*)(Xb + (m0 + r) * C_ + k0 + c16 * 8);
            uint4 vb = *(const uint4*)(Wt + (n0 + r) * C_ + k0 + c16 * 8);
            int off = r * 128 + ((c16 * 16) ^ ((r & 7) << 4));
            *(uint4*)(lsAb + off) = va;
            *(uint4*)(lsBb + off) = vb;
        }
        __syncthreads();
#pragma unroll
        for (int kk = 0; kk < 2; ++kk) {
            bf16x8 af[4], bfr[4];
            const int kb = (kk * 32 + lg * 8) * 2;
#pragma unroll
            for (int i = 0; i < 4; ++i) {
                int ra = wm * 64 + i * 16 + lr;
                af[i] = *(const bf16x8*)(lsAb + ra * 128 + (kb ^ ((ra & 7) << 4)));
                int rb = wn * 64 + i * 16 + lr;
                bfr[i] = *(const bf16x8*)(lsBb + rb * 128 + (kb ^ ((rb & 7) << 4)));
            }
#pragma unroll
            for (int mi = 0; mi < 4; ++mi)
#pragma unroll
                for (int nj = 0; nj < 4; ++nj)
                    acc[mi][nj] = __builtin_amdgcn_mfma_f32_16x16x32_bf16(af[mi], bfr[nj], acc[mi][nj], 0, 0, 0);
        }
    }
    const float scale = (z == 0) ? 0.125f : 1.0f;
    const int mbase = m0 + wm * 64, nbase = n0 + wn * 64;
    if (z < 2) {
        ushort_t* outp = (z == 0) ? Qo : Ko;
#pragma unroll
        for (int mi = 0; mi < 4; ++mi) {
#pragma unroll
            for (int nj = 0; nj < 4; ++nj) {
                int col = nbase + nj * 16 + lr;
                int h = col >> 6, d = col & 63;
                float bv_ = bias[col];
#pragma unroll
                for (int j = 0; j < 4; ++j) {
                    int m = mbase + mi * 16 + lg * 4 + j;
                    int bb = m >> 12, t = m & 4095;
                    outp[((bb * H_ + h) * T_ + t) * D_ + d] = f2bf((acc[mi][nj][j] + bv_) * scale);
                }
            }
        }
    } else {
        // V stored transposed: Vo[((b*H+h)*D + d)*T + t]
#pragma unroll
        for (int mi = 0; mi < 4; ++mi) {
            int m0j = mbase + mi * 16 + lg * 4;
            int bb = m0j >> 12, t0 = m0j & 4095;
#pragma unroll
            for (int nj = 0; nj < 4; ++nj) {
                int col = nbase + nj * 16 + lr;
                int h = col >> 6, d = col & 63;
                float bv_ = bias[col];
                ushort4 pk;
                pk.x = f2bf(acc[mi][nj][0] + bv_);
                pk.y = f2bf(acc[mi][nj][1] + bv_);
                pk.z = f2bf(acc[mi][nj][2] + bv_);
                pk.w = f2bf(acc[mi][nj][3] + bv_);
                *(ushort4*)(Vo + ((size_t)(bb * H_ + h) * D_ + d) * T_ + t0) = pk;
            }
        }
    }
}

// flash attention: grid (32 qtiles, 24 bh); 4 waves x 32 q-rows; KVBLK=64
// V input is transposed [B,H,D,T]
__global__ __launch_bounds__(256) void k_flash(const ushort_t* __restrict__ Q,
                                               const ushort_t* __restrict__ K,
                                               const ushort_t* __restrict__ Vt,
                                               ushort_t* __restrict__ AO) {
    __shared__ ushort_t lsK[64 * 64];
    __shared__ ushort_t lsV[64 * 64];
    __shared__ ushort_t lsP[4 * 32 * 64];
    char* lsKb = (char*)lsK;
    char* lsVb = (char*)lsV;
    const int bh = blockIdx.y;
    const int b = bh / H_, h = bh % H_;
    const int qt = 31 - (int)blockIdx.x;  // big tiles first
    const int q0 = qt * 128;
    const int tid = threadIdx.x, w = tid >> 6, lane = tid & 63, lg = lane >> 4, lr = lane & 15;
    char* lsPb = (char*)(lsP + w * 32 * 64);
    const ushort_t* qb = Q + (size_t)bh * T_ * D_;
    const ushort_t* kb = K + (size_t)bh * T_ * D_;
    const ushort_t* vtb = Vt + (size_t)bh * D_ * T_;   // [D][T]
    const int wave_qmin = q0 + w * 32;
    const int wave_qmax = wave_qmin + 31;
    bf16x8 aq[2][2];
#pragma unroll
    for (int mt = 0; mt < 2; ++mt)
#pragma unroll
        for (int kk = 0; kk < 2; ++kk)
            aq[mt][kk] = *(const bf16x8*)(qb + (size_t)(wave_qmin + mt * 16 + lr) * D_ + kk * 32 + lg * 8);
    float m_s[2][4], l_s[2][4];
    f4v o[2][4] = {};
#pragma unroll
    for (int mt = 0; mt < 2; ++mt)
#pragma unroll
        for (int j = 0; j < 4; ++j) { m_s[mt][j] = -1e30f; l_s[mt][j] = 0.f; }

    const int ntiles = (q0 + 128) >> 6;
    for (int kt = 0; kt < ntiles; ++kt) {
        const int kv0 = kt * 64;
        __syncthreads();
        // stage K rows [kv][d] and V^T rows [d][kv], both swizzled
#pragma unroll
        for (int i = 0; i < 2; ++i) {
            int s = tid + 256 * i;
            int r = s >> 3, c = s & 7;  // r: 0..63, c: 8-elem chunk
            uint4 vk = *(const uint4*)(kb + (size_t)(kv0 + r) * D_ + c * 8);
            *(uint4*)(lsKb + r * 128 + ((c * 16) ^ ((r & 7) << 4))) = vk;
            uint4 vv = *(const uint4*)(vtb + (size_t)r * T_ + kv0 + c * 8);
            *(uint4*)(lsVb + r * 128 + ((c * 16) ^ ((r & 7) << 4))) = vv;
        }
        __syncthreads();
        if (kv0 > wave_qmax) continue;
        // S = Q K^T
        f4v sf[2][4] = {};
#pragma unroll
        for (int kk = 0; kk < 2; ++kk) {
            const int kbyte = (kk * 32 + lg * 8) * 2;
            bf16x8 bk_[4];
#pragma unroll
            for (int nt = 0; nt < 4; ++nt) {
                int rk = nt * 16 + lr;
                bk_[nt] = *(const bf16x8*)(lsKb + rk * 128 + (kbyte ^ ((rk & 7) << 4)));
            }
#pragma unroll
            for (int mt = 0; mt < 2; ++mt)
#pragma unroll
                for (int nt = 0; nt < 4; ++nt)
                    sf[mt][nt] = __builtin_amdgcn_mfma_f32_16x16x32_bf16(aq[mt][kk], bk_[nt], sf[mt][nt], 0, 0, 0);
        }
        if (kv0 + 63 > wave_qmin) {  // causal mask with finite sentinel
#pragma unroll
            for (int mt = 0; mt < 2; ++mt)
#pragma unroll
                for (int nt = 0; nt < 4; ++nt)
#pragma unroll
                    for (int j = 0; j < 4; ++j) {
                        int qg = wave_qmin + mt * 16 + lg * 4 + j;
                        int kg = kv0 + nt * 16 + lr;
                        if (kg > qg) sf[mt][nt][j] = -1e30f;
                    }
        }
        // online softmax (wave-parallel, 16-lane butterflies) + P -> LDS (bf16)
#pragma unroll
        for (int mt = 0; mt < 2; ++mt) {
#pragma unroll
            for (int j = 0; j < 4; ++j) {
                float rm = fmaxf(fmaxf(sf[mt][0][j], sf[mt][1][j]), fmaxf(sf[mt][2][j], sf[mt][3][j]));
                rm = fmaxf(rm, __shfl_xor(rm, 1));
                rm = fmaxf(rm, __shfl_xor(rm, 2));
                rm = fmaxf(rm, __shfl_xor(rm, 4));
                rm = fmaxf(rm, __shfl_xor(rm, 8));
                float mo = m_s[mt][j];
                float mn = fmaxf(mo, rm);
                float alpha = __expf(mo - mn);
                float rs = 0.f;
                int prow = mt * 16 + lg * 4 + j;
#pragma unroll
                for (int nt = 0; nt < 4; ++nt) {
                    float p = __expf(sf[mt][nt][j] - mn);
                    rs += p;
                    int cbyte = (nt * 16 + lr) * 2;
                    *(ushort_t*)(lsPb + prow * 128 + (cbyte ^ ((prow & 7) << 4))) = f2bf(p);
                }
                rs += __shfl_xor(rs, 1);
                rs += __shfl_xor(rs, 2);
                rs += __shfl_xor(rs, 4);
                rs += __shfl_xor(rs, 8);
                l_s[mt][j] = l_s[mt][j] * alpha + rs;
                m_s[mt][j] = mn;
#pragma unroll
                for (int nt = 0; nt < 4; ++nt) o[mt][nt][j] *= alpha;
            }
        }
        // O += P V  (A-frags from lsP, B-frags from lsV = V^T)
#pragma unroll
        for (int kk = 0; kk < 2; ++kk) {
            const int kvbyte = (kk * 32 + lg * 8) * 2;
            bf16x8 ap[2], bv_[4];
#pragma unroll
            for (int mt = 0; mt < 2; ++mt) {
                int rp = mt * 16 + lr;
                ap[mt] = *(const bf16x8*)(lsPb + rp * 128 + (kvbyte ^ ((rp & 7) << 4)));
            }
#pragma unroll
            for (int nt = 0; nt < 4; ++nt) {
                int rd = nt * 16 + lr;
                bv_[nt] = *(const bf16x8*)(lsVb + rd * 128 + (kvbyte ^ ((rd & 7) << 4)));
            }
#pragma unroll
            for (int mt = 0; mt < 2; ++mt)
#pragma unroll
                for (int nt = 0; nt < 4; ++nt)
                    o[mt][nt] = __builtin_amdgcn_mfma_f32_16x16x32_bf16(ap[mt], bv_[nt], o[mt][nt], 0, 0, 0);
        }
    }
    // epilogue: normalize + store to [B,T,C] bf16
    ushort_t* aob = AO + (size_t)b * T_ * C_ + h * D_;
#pragma unroll
    for (int mt = 0; mt < 2; ++mt) {
#pragma unroll
        for (int j = 0; j < 4; ++j) {
            float inv = 1.f / l_s[mt][j];
            int qg = wave_qmin + mt * 16 + lg * 4 + j;
#pragma unroll
            for (int nt = 0; nt < 4; ++nt) {
                int d = nt * 16 + lr;
                aob[(size_t)qg * C_ + d] = f2bf(o[mt][nt][j] * inv);
            }
        }
    }
}

// final projection: fp32 out = AO @ Wo^T(stored) + bo
__global__ __launch_bounds__(256) void k_gemm_out(const ushort_t* __restrict__ Ab,
                                                  const ushort_t* __restrict__ Wt,
                                                  const float* __restrict__ bo,
                                                  float* __restrict__ Out) {
    __shared__ ushort_t lsA[128 * 64];
    __shared__ ushort_t lsB[128 * 64];
    char* lsAb = (char*)lsA;
    char* lsBb = (char*)lsB;
    const int m0 = blockIdx.x * 128, n0 = blockIdx.y * 128;
    const int tid = threadIdx.x;
    const int w = tid >> 6, lane = tid & 63, lg = lane >> 4, lr = lane & 15;
    const int wm = w >> 1, wn = w & 1;
    f4v acc[4][4] = {};
    for (int ks = 0; ks < 12; ++ks) {
        const int k0 = ks * 64;
        __syncthreads();
#pragma unroll
        for (int i = 0; i < 4; ++i) {
            int s = tid + 256 * i;
            int r = s >> 3, c16 = s & 7;
            uint4 va = *(const uint4*)(Ab + (m0 + r) * C_ + k0 + c16 * 8);
            uint4 vb = *(const uint4*)(Wt + (n0 + r) * C_ + k0 + c16 * 8);
            int off = r * 128 + ((c16 * 16) ^ ((r & 7) << 4));
            *(uint4*)(lsAb + off) = va;
            *(uint4*)(lsBb + off) = vb;
        }
        __syncthreads();
#pragma unroll
        for (int kk = 0; kk < 2; ++kk) {
            bf16x8 af[4], bfr[4];
            const int kb = (kk * 32 + lg * 8) * 2;
#pragma unroll
            for (int i = 0; i < 4; ++i) {
                int ra = wm * 64 + i * 16 + lr;
                af[i] = *(const bf16x8*)(lsAb + ra * 128 + (kb ^ ((ra & 7) << 4)));
                int rb = wn * 64 + i * 16 + lr;
                bfr[i] = *(const bf16x8*)(lsBb + rb * 128 + (kb ^ ((rb & 7) << 4)));
            }
#pragma unroll
            for (int mi = 0; mi < 4; ++mi)
#pragma unroll
                for (int nj = 0; nj < 4; ++nj)
                    acc[mi][nj] = __builtin_amdgcn_mfma_f32_16x16x32_bf16(af[mi], bfr[nj], acc[mi][nj], 0, 0, 0);
        }
    }
    const int mbase = m0 + wm * 64, nbase = n0 + wn * 64;
#pragma unroll
    for (int mi = 0; mi < 4; ++mi) {
#pragma unroll
        for (int nj = 0; nj < 4; ++nj) {
            int col = nbase + nj * 16 + lr;
            float bv_ = bo[col];
#pragma unroll
            for (int j = 0; j < 4; ++j) {
                int m = mbase + mi * 16 + lg * 4 + j;
                Out[(size_t)m * C_ + col] = acc[mi][nj][j] + bv_;
            }
        }
    }
}

extern "C" void kernel_launch(void* const* d_in, const int* in_sizes, int n_in,
                              void* d_out, int out_size, void* d_ws, size_t ws_size,
                              hipStream_t stream) {
    const float* x  = (const float*)d_in[0];
    const float* Wq = (const float*)d_in[1];
    const float* bq = (const float*)d_in[2];
    const float* Wk = (const float*)d_in[3];
    const float* bk = (const float*)d_in[4];
    const float* Wv = (const float*)d_in[5];
    const float* bv = (const float*)d_in[6];
    const float* Wo = (const float*)d_in[7];
    const float* bo = (const float*)d_in[8];
    float* out = (float*)d_out;
    char* ws = (char*)d_ws;
    if (ws_size < (size_t)WS_TOTAL) return;  // insufficient scratch

    ushort_t* Xb = (ushort_t*)(ws + WS_XB);
    ushort_t* Wt = (ushort_t*)(ws + WS_WT);
    ushort_t* Qb = (ushort_t*)(ws + WS_Q);
    ushort_t* Kb = (ushort_t*)(ws + WS_K);
    ushort_t* Vb = (ushort_t*)(ws + WS_V);
    ushort_t* Ao = (ushort_t*)(ws + WS_AO);

    k_convert_x<<<dim3(BT_ * C_ / 4 / 256), 256, 0, stream>>>(x, Xb, BT_ * C_ / 4);
    k_wt<<<dim3(24, 24, 4), 256, 0, stream>>>(Wq, Wk, Wv, Wo, Wt);
    k_gemm_qkv<<<dim3(64, 6, 3), 256, 0, stream>>>(Xb, Wt, bq, bk, bv, Qb, Kb, Vb);
    k_flash<<<dim3(32, 24), 256, 0, stream>>>(Qb, Kb, Vb, Ao);
    k_gemm_out<<<dim3(64, 6), 256, 0, stream>>>(Ao, Wt + 3 * C_ * C_, bo, out);
}

// Round 3
// 334.048 us; speedup vs baseline: 1.5676x; 1.5676x over previous
//
#include <hip/hip_runtime.h>

typedef unsigned short ushort_t;
typedef __bf16 bf16x8 __attribute__((ext_vector_type(8)));
typedef float f4v __attribute__((ext_vector_type(4)));

#define B_ 2
#define T_ 4096
#define C_ 768
#define H_ 12
#define D_ 64
#define BT_ (B_*T_)

// workspace layout (bytes)
#define XB_SZ   (BT_*C_*2)            // 12,582,912
#define WT_SZ   (C_*C_*2)             // 1,179,648
#define QKV_SZ  (BT_*C_*2)            // 12,582,912
#define WS_XB   0
#define WS_WT   (WS_XB + XB_SZ)
#define WS_Q    (WS_WT + 4*WT_SZ)
#define WS_K    (WS_Q + QKV_SZ)
#define WS_V    (WS_K + QKV_SZ)
#define WS_AO   (WS_V + QKV_SZ)
#define WS_TOTAL (WS_AO + QKV_SZ)

__device__ __forceinline__ ushort_t f2bf(float f) {
    unsigned u = __float_as_uint(f);
    u += 0x7FFFu + ((u >> 16) & 1u);
    return (ushort_t)(u >> 16);
}

__global__ __launch_bounds__(256) void k_convert_x(const float* __restrict__ x,
                                                   ushort_t* __restrict__ xb, int n4) {
    int i = blockIdx.x * 256 + threadIdx.x;
    if (i >= n4) return;
    float4 v = ((const float4*)x)[i];
    ushort4 o;
    o.x = f2bf(v.x); o.y = f2bf(v.y); o.z = f2bf(v.z); o.w = f2bf(v.w);
    ((ushort4*)xb)[i] = o;
}

// Wt[n][k] = bf16(W[k][n]), four weights
__global__ __launch_bounds__(256) void k_wt(const float* __restrict__ w0,
                                            const float* __restrict__ w1,
                                            const float* __restrict__ w2,
                                            const float* __restrict__ w3,
                                            ushort_t* __restrict__ wt) {
    __shared__ float tile[32][33];
    int wi = blockIdx.z;
    const float* W = (wi == 0) ? w0 : (wi == 1) ? w1 : (wi == 2) ? w2 : w3;
    ushort_t* out = wt + wi * C_ * C_;
    int k0 = blockIdx.x * 32, n0 = blockIdx.y * 32;
    int tx = threadIdx.x & 31, ty = threadIdx.x >> 5;  // ty 0..7
#pragma unroll
    for (int i = 0; i < 4; ++i) {
        int kr = ty * 4 + i;
        tile[kr][tx] = W[(k0 + kr) * C_ + n0 + tx];
    }
    __syncthreads();
#pragma unroll
    for (int i = 0; i < 4; ++i) {
        int nr = ty * 4 + i;
        out[(n0 + nr) * C_ + k0 + tx] = f2bf(tile[tx][nr]);
    }
}

// 128x128 tile GEMM, 4 waves (2x2), wave computes 64x64; BK=64; swizzled LDS.
// z=0:Q (scaled 0.125), z=1:K, z=2:V stored transposed [B,H,D,T]
__global__ __launch_bounds__(256) void k_gemm_qkv(
    const ushort_t* __restrict__ Xb, const ushort_t* __restrict__ WtAll,
    const float* __restrict__ bq, const float* __restrict__ bk, const float* __restrict__ bv,
    ushort_t* __restrict__ Qo, ushort_t* __restrict__ Ko, ushort_t* __restrict__ Vo) {
    __shared__ ushort_t lsA[128 * 64];
    __shared__ ushort_t lsB[128 * 64];
    char* lsAb = (char*)lsA;
    char* lsBb = (char*)lsB;
    const int z = blockIdx.z;
    const ushort_t* Wt = WtAll + z * C_ * C_;
    const float* bias = (z == 0) ? bq : (z == 1) ? bk : bv;
    const int m0 = blockIdx.x * 128, n0 = blockIdx.y * 128;
    const int tid = threadIdx.x;
    const int w = tid >> 6, lane = tid & 63, lg = lane >> 4, lr = lane & 15;
    const int wm = w >> 1, wn = w & 1;
    f4v acc[4][4] = {};
    for (int ks = 0; ks < 12; ++ks) {
        const int k0 = ks * 64;
        __syncthreads();
#pragma unroll
        for (int i = 0; i < 4; ++i) {
            int s = tid + 256 * i;
            int r = s >> 3, c16 = s & 7;
            uint4 va = *(const uint4*)(Xb + (m0 + r) * C_ + k0 + c16 * 8);
            uint4 vb = *(const uint4*)(Wt + (n0 + r) * C_ + k0 + c16 * 8);
            int off = r * 128 + ((c16 * 16) ^ ((r & 7) << 4));
            *(uint4*)(lsAb + off) = va;
            *(uint4*)(lsBb + off) = vb;
        }
        __syncthreads();
#pragma unroll
        for (int kk = 0; kk < 2; ++kk) {
            bf16x8 af[4], bfr[4];
            const int kb = (kk * 32 + lg * 8) * 2;
#pragma unroll
            for (int i = 0; i < 4; ++i) {
                int ra = wm * 64 + i * 16 + lr;
                af[i] = *(const bf16x8*)(lsAb + ra * 128 + (kb ^ ((ra & 7) << 4)));
                int rb = wn * 64 + i * 16 + lr;
                bfr[i] = *(const bf16x8*)(lsBb + rb * 128 + (kb ^ ((rb & 7) << 4)));
            }
#pragma unroll
            for (int mi = 0; mi < 4; ++mi)
#pragma unroll
                for (int nj = 0; nj < 4; ++nj)
                    acc[mi][nj] = __builtin_amdgcn_mfma_f32_16x16x32_bf16(af[mi], bfr[nj], acc[mi][nj], 0, 0, 0);
        }
    }
    const float scale = (z == 0) ? 0.125f : 1.0f;
    const int mbase = m0 + wm * 64, nbase = n0 + wn * 64;
    if (z < 2) {
        ushort_t* outp = (z == 0) ? Qo : Ko;
#pragma unroll
        for (int mi = 0; mi < 4; ++mi) {
#pragma unroll
            for (int nj = 0; nj < 4; ++nj) {
                int col = nbase + nj * 16 + lr;
                int h = col >> 6, d = col & 63;
                float bv_ = bias[col];
#pragma unroll
                for (int j = 0; j < 4; ++j) {
                    int m = mbase + mi * 16 + lg * 4 + j;
                    int bb = m >> 12, t = m & 4095;
                    outp[((bb * H_ + h) * T_ + t) * D_ + d] = f2bf((acc[mi][nj][j] + bv_) * scale);
                }
            }
        }
    } else {
        // V stored transposed: Vo[((b*H+h)*D + d)*T + t]
#pragma unroll
        for (int mi = 0; mi < 4; ++mi) {
            int m0j = mbase + mi * 16 + lg * 4;
            int bb = m0j >> 12, t0 = m0j & 4095;
#pragma unroll
            for (int nj = 0; nj < 4; ++nj) {
                int col = nbase + nj * 16 + lr;
                int h = col >> 6, d = col & 63;
                float bv_ = bias[col];
                ushort4 pk;
                pk.x = f2bf(acc[mi][nj][0] + bv_);
                pk.y = f2bf(acc[mi][nj][1] + bv_);
                pk.z = f2bf(acc[mi][nj][2] + bv_);
                pk.w = f2bf(acc[mi][nj][3] + bv_);
                *(ushort4*)(Vo + ((size_t)(bb * H_ + h) * D_ + d) * T_ + t0) = pk;
            }
        }
    }
}

// flash attention: QB=64, 4 waves x 16 q-rows; KVBLK=64; grid flattened
// x = 1536 blocks ordered big-work-first: qt = 63 - idx/24, bh = idx%24.
// V input is transposed [B,H,D,T]
__global__ __launch_bounds__(256) void k_flash(const ushort_t* __restrict__ Q,
                                               const ushort_t* __restrict__ K,
                                               const ushort_t* __restrict__ Vt,
                                               ushort_t* __restrict__ AO) {
    __shared__ ushort_t lsK[64 * 64];
    __shared__ ushort_t lsV[64 * 64];
    __shared__ ushort_t lsP[4 * 16 * 64];
    char* lsKb = (char*)lsK;
    char* lsVb = (char*)lsV;
    const int idx = blockIdx.x;
    const int qt = 63 - idx / 24;   // biggest causal spans first
    const int bh = idx % 24;
    const int b = bh / H_, h = bh % H_;
    const int q0 = qt * 64;
    const int tid = threadIdx.x, w = tid >> 6, lane = tid & 63, lg = lane >> 4, lr = lane & 15;
    char* lsPb = (char*)(lsP + w * 16 * 64);
    const ushort_t* qb = Q + (size_t)bh * T_ * D_;
    const ushort_t* kb = K + (size_t)bh * T_ * D_;
    const ushort_t* vtb = Vt + (size_t)bh * D_ * T_;   // [D][T]
    const int wave_qmin = q0 + w * 16;
    bf16x8 aq[2];
#pragma unroll
    for (int kk = 0; kk < 2; ++kk)
        aq[kk] = *(const bf16x8*)(qb + (size_t)(wave_qmin + lr) * D_ + kk * 32 + lg * 8);
    float m_s[4], l_s[4];
    f4v o[4] = {};
#pragma unroll
    for (int j = 0; j < 4; ++j) { m_s[j] = -1e30f; l_s[j] = 0.f; }

    const int ntiles = qt + 1;
    for (int kt = 0; kt < ntiles; ++kt) {
        const int kv0 = kt * 64;
        __syncthreads();
        // stage K rows [kv][d] and V^T rows [d][kv], both swizzled
#pragma unroll
        for (int i = 0; i < 2; ++i) {
            int s = tid + 256 * i;
            int r = s >> 3, c = s & 7;  // r: 0..63, c: 8-elem chunk
            uint4 vk = *(const uint4*)(kb + (size_t)(kv0 + r) * D_ + c * 8);
            *(uint4*)(lsKb + r * 128 + ((c * 16) ^ ((r & 7) << 4))) = vk;
            uint4 vv = *(const uint4*)(vtb + (size_t)r * T_ + kv0 + c * 8);
            *(uint4*)(lsVb + r * 128 + ((c * 16) ^ ((r & 7) << 4))) = vv;
        }
        __syncthreads();
        // S = Q K^T  (16 q-rows x 64 kv)
        f4v sf[4] = {};
#pragma unroll
        for (int kk = 0; kk < 2; ++kk) {
            const int kbyte = (kk * 32 + lg * 8) * 2;
            bf16x8 bk_[4];
#pragma unroll
            for (int nt = 0; nt < 4; ++nt) {
                int rk = nt * 16 + lr;
                bk_[nt] = *(const bf16x8*)(lsKb + rk * 128 + (kbyte ^ ((rk & 7) << 4)));
            }
#pragma unroll
            for (int nt = 0; nt < 4; ++nt)
                sf[nt] = __builtin_amdgcn_mfma_f32_16x16x32_bf16(aq[kk], bk_[nt], sf[nt], 0, 0, 0);
        }
        if (kv0 + 63 > wave_qmin) {  // diagonal tile: causal mask, finite sentinel
#pragma unroll
            for (int nt = 0; nt < 4; ++nt)
#pragma unroll
                for (int j = 0; j < 4; ++j) {
                    int qg = wave_qmin + lg * 4 + j;
                    int kg = kv0 + nt * 16 + lr;
                    if (kg > qg) sf[nt][j] = -1e30f;
                }
        }
        // online softmax (wave-parallel, 16-lane butterflies) + P -> LDS (bf16)
#pragma unroll
        for (int j = 0; j < 4; ++j) {
            float rm = fmaxf(fmaxf(sf[0][j], sf[1][j]), fmaxf(sf[2][j], sf[3][j]));
            rm = fmaxf(rm, __shfl_xor(rm, 1));
            rm = fmaxf(rm, __shfl_xor(rm, 2));
            rm = fmaxf(rm, __shfl_xor(rm, 4));
            rm = fmaxf(rm, __shfl_xor(rm, 8));
            float mo = m_s[j];
            float mn = fmaxf(mo, rm);
            float alpha = __expf(mo - mn);
            float rs = 0.f;
            int prow = lg * 4 + j;
#pragma unroll
            for (int nt = 0; nt < 4; ++nt) {
                float p = __expf(sf[nt][j] - mn);
                rs += p;
                int cbyte = (nt * 16 + lr) * 2;
                *(ushort_t*)(lsPb + prow * 128 + (cbyte ^ ((prow & 7) << 4))) = f2bf(p);
            }
            rs += __shfl_xor(rs, 1);
            rs += __shfl_xor(rs, 2);
            rs += __shfl_xor(rs, 4);
            rs += __shfl_xor(rs, 8);
            l_s[j] = l_s[j] * alpha + rs;
            m_s[j] = mn;
#pragma unroll
            for (int nt = 0; nt < 4; ++nt) o[nt][j] *= alpha;
        }
        // O += P V  (A-frag from lsP, B-frags from lsV = V^T)
#pragma unroll
        for (int kk = 0; kk < 2; ++kk) {
            const int kvbyte = (kk * 32 + lg * 8) * 2;
            bf16x8 ap, bv_[4];
            ap = *(const bf16x8*)(lsPb + lr * 128 + (kvbyte ^ ((lr & 7) << 4)));
#pragma unroll
            for (int nt = 0; nt < 4; ++nt) {
                int rd = nt * 16 + lr;
                bv_[nt] = *(const bf16x8*)(lsVb + rd * 128 + (kvbyte ^ ((rd & 7) << 4)));
            }
#pragma unroll
            for (int nt = 0; nt < 4; ++nt)
                o[nt] = __builtin_amdgcn_mfma_f32_16x16x32_bf16(ap, bv_[nt], o[nt], 0, 0, 0);
        }
    }
    // epilogue: normalize + store to [B,T,C] bf16
    ushort_t* aob = AO + (size_t)b * T_ * C_ + h * D_;
#pragma unroll
    for (int j = 0; j < 4; ++j) {
        float inv = 1.f / l_s[j];
        int qg = wave_qmin + lg * 4 + j;
#pragma unroll
        for (int nt = 0; nt < 4; ++nt) {
            int d = nt * 16 + lr;
            aob[(size_t)qg * C_ + d] = f2bf(o[nt][j] * inv);
        }
    }
}

// final projection: fp32 out = AO @ Wo^T(stored) + bo
__global__ __launch_bounds__(256) void k_gemm_out(const ushort_t* __restrict__ Ab,
                                                  const ushort_t* __restrict__ Wt,
                                                  const float* __restrict__ bo,
                                                  float* __restrict__ Out) {
    __shared__ ushort_t lsA[128 * 64];
    __shared__ ushort_t lsB[128 * 64];
    char* lsAb = (char*)lsA;
    char* lsBb = (char*)lsB;
    const int m0 = blockIdx.x * 128, n0 = blockIdx.y * 128;
    const int tid = threadIdx.x;
    const int w = tid >> 6, lane = tid & 63, lg = lane >> 4, lr = lane & 15;
    const int wm = w >> 1, wn = w & 1;
    f4v acc[4][4] = {};
    for (int ks = 0; ks < 12; ++ks) {
        const int k0 = ks * 64;
        __syncthreads();
#pragma unroll
        for (int i = 0; i < 4; ++i) {
            int s = tid + 256 * i;
            int r = s >> 3, c16 = s & 7;
            uint4 va = *(const uint4*)(Ab + (m0 + r) * C_ + k0 + c16 * 8);
            uint4 vb = *(const uint4*)(Wt + (n0 + r) * C_ + k0 + c16 * 8);
            int off = r * 128 + ((c16 * 16) ^ ((r & 7) << 4));
            *(uint4*)(lsAb + off) = va;
            *(uint4*)(lsBb + off) = vb;
        }
        __syncthreads();
#pragma unroll
        for (int kk = 0; kk < 2; ++kk) {
            bf16x8 af[4], bfr[4];
            const int kb = (kk * 32 + lg * 8) * 2;
#pragma unroll
            for (int i = 0; i < 4; ++i) {
                int ra = wm * 64 + i * 16 + lr;
                af[i] = *(const bf16x8*)(lsAb + ra * 128 + (kb ^ ((ra & 7) << 4)));
                int rb = wn * 64 + i * 16 + lr;
                bfr[i] = *(const bf16x8*)(lsBb + rb * 128 + (kb ^ ((rb & 7) << 4)));
            }
#pragma unroll
            for (int mi = 0; mi < 4; ++mi)
#pragma unroll
                for (int nj = 0; nj < 4; ++nj)
                    acc[mi][nj] = __builtin_amdgcn_mfma_f32_16x16x32_bf16(af[mi], bfr[nj], acc[mi][nj], 0, 0, 0);
        }
    }
    const int mbase = m0 + wm * 64, nbase = n0 + wn * 64;
#pragma unroll
    for (int mi = 0; mi < 4; ++mi) {
#pragma unroll
        for (int nj = 0; nj < 4; ++nj) {
            int col = nbase + nj * 16 + lr;
            float bv_ = bo[col];
#pragma unroll
            for (int j = 0; j < 4; ++j) {
                int m = mbase + mi * 16 + lg * 4 + j;
                Out[(size_t)m * C_ + col] = acc[mi][nj][j] + bv_;
            }
        }
    }
}

extern "C" void kernel_launch(void* const* d_in, const int* in_sizes, int n_in,
                              void* d_out, int out_size, void* d_ws, size_t ws_size,
                              hipStream_t stream) {
    const float* x  = (const float*)d_in[0];
    const float* Wq = (const float*)d_in[1];
    const float* bq = (const float*)d_in[2];
    const float* Wk = (const float*)d_in[3];
    const float* bk = (const float*)d_in[4];
    const float* Wv = (const float*)d_in[5];
    const float* bv = (const float*)d_in[6];
    const float* Wo = (const float*)d_in[7];
    const float* bo = (const float*)d_in[8];
    float* out = (float*)d_out;
    char* ws = (char*)d_ws;
    if (ws_size < (size_t)WS_TOTAL) return;  // insufficient scratch

    ushort_t* Xb = (ushort_t*)(ws + WS_XB);
    ushort_t* Wt = (ushort_t*)(ws + WS_WT);
    ushort_t* Qb = (ushort_t*)(ws + WS_Q);
    ushort_t* Kb = (ushort_t*)(ws + WS_K);
    ushort_t* Vb = (ushort_t*)(ws + WS_V);
    ushort_t* Ao = (ushort_t*)(ws + WS_AO);

    k_convert_x<<<dim3(BT_ * C_ / 4 / 256), 256, 0, stream>>>(x, Xb, BT_ * C_ / 4);
    k_wt<<<dim3(24, 24, 4), 256, 0, stream>>>(Wq, Wk, Wv, Wo, Wt);
    k_gemm_qkv<<<dim3(64, 6, 3), 256, 0, stream>>>(Xb, Wt, bq, bk, bv, Qb, Kb, Vb);
    k_flash<<<dim3(64 * 24), 256, 0, stream>>>(Qb, Kb, Vb, Ao);
    k_gemm_out<<<dim3(64, 6), 256, 0, stream>>>(Ao, Wt + 3 * C_ * C_, bo, out);
}